// Round 12
// baseline (98.586 us; speedup 1.0000x reference)
//
#include <hip/hip_runtime.h>
#include <hip/hip_bf16.h>
#include <cstdint>

typedef __hip_bfloat16 bf16;
typedef __attribute__((ext_vector_type(8))) __bf16 bf16x8;
typedef __attribute__((ext_vector_type(4))) float f32x4;

static __device__ __forceinline__ void gload_lds16(const void* g, void* l) {
  __builtin_amdgcn_global_load_lds(
      (const __attribute__((address_space(1))) uint32_t*)g,
      (__attribute__((address_space(3))) uint32_t*)l, 16, 0, 0);
}

// ---------------- merged prep: x->bf16 | w1^T->bf16 | w2^T->bf16 ----------------
__global__ __launch_bounds__(256)
void prep_kernel(const float* __restrict__ x, const float* __restrict__ w1,
                 const float* __restrict__ w2, bf16* __restrict__ xb,
                 bf16* __restrict__ w1t, bf16* __restrict__ w2t) {
  __shared__ float tile[32][33];
  const int lin = blockIdx.x;
  const int t = threadIdx.x;
  if (lin < 4096) {  // x conversion: 1M float4
    const int i = lin * 256 + t;
    const float4 v = reinterpret_cast<const float4*>(x)[i];
    ushort4 o;
    o.x = __builtin_bit_cast(unsigned short, __float2bfloat16(v.x));
    o.y = __builtin_bit_cast(unsigned short, __float2bfloat16(v.y));
    o.z = __builtin_bit_cast(unsigned short, __float2bfloat16(v.z));
    o.w = __builtin_bit_cast(unsigned short, __float2bfloat16(v.w));
    reinterpret_cast<ushort4*>(xb)[i] = o;
    return;
  }
  const float* in;
  bf16* out;
  int R, C, bx, by;
  if (lin < 10240) {
    const int tl = lin - 4096;
    in = w1; out = w1t; R = 2048; C = 3072; bx = tl % 96; by = tl / 96;
  } else {
    const int tl = lin - 10240;
    in = w2; out = w2t; R = 2048; C = 2048; bx = tl & 63; by = tl >> 6;
  }
  const int c0 = bx * 32, r0 = by * 32;
  const int tx = t & 31, ty = t >> 5;
#pragma unroll
  for (int i = 0; i < 4; ++i)
    tile[ty + i * 8][tx] = in[(size_t)(r0 + ty + i * 8) * C + c0 + tx];
  __syncthreads();
#pragma unroll
  for (int i = 0; i < 4; ++i)
    out[(size_t)(c0 + ty + i * 8) * R + r0 + tx] = __float2bfloat16(tile[tx][ty + i * 8]);
}

// ---------------- RoPE in-place for K (bf16) ----------------
template <int NH, int SSHIFT>
__global__ void rope_kernel(bf16* __restrict__ buf, const float* __restrict__ cosT,
                            const float* __restrict__ sinT) {
  const int idx = blockIdx.x * 256 + threadIdx.x;
  const int c = idx & 3;
  const int h = (idx >> 2) & (NH - 1);
  const int s = idx >> SSHIFT;
  bf16* p = buf + (size_t)s * (NH * 64) + h * 64 + c * 8;
  bf16x8 v1 = *reinterpret_cast<bf16x8*>(p);
  bf16x8 v2 = *reinterpret_cast<bf16x8*>(p + 32);
  const float4 c0 = *reinterpret_cast<const float4*>(&cosT[s * 32 + c * 8]);
  const float4 c1 = *reinterpret_cast<const float4*>(&cosT[s * 32 + c * 8 + 4]);
  const float4 s0 = *reinterpret_cast<const float4*>(&sinT[s * 32 + c * 8]);
  const float4 s1 = *reinterpret_cast<const float4*>(&sinT[s * 32 + c * 8 + 4]);
  const float cs[8] = {c0.x, c0.y, c0.z, c0.w, c1.x, c1.y, c1.z, c1.w};
  const float sn[8] = {s0.x, s0.y, s0.z, s0.w, s1.x, s1.y, s1.z, s1.w};
  bf16x8 o1, o2;
#pragma unroll
  for (int e = 0; e < 8; ++e) {
    const float x1 = (float)v1[e], x2 = (float)v2[e];
    o1[e] = (__bf16)(x1 * cs[e] - x2 * sn[e]);
    o2[e] = (__bf16)(x2 * cs[e] + x1 * sn[e]);
  }
  *reinterpret_cast<bf16x8*>(p) = o1;
  *reinterpret_cast<bf16x8*>(p + 32) = o2;
}

// ---------------- GEMM1: BM=128 BN=192 BK=64, 8 waves, 3-deep (R8-proven loop) ----------------
__global__ __launch_bounds__(512, 1)
void gemm1_kernel(const bf16* __restrict__ A, const bf16* __restrict__ Bt,
                  const float* __restrict__ bias,
                  bf16* __restrict__ qb, bf16* __restrict__ kb, bf16* __restrict__ vt) {
  extern __shared__ __align__(16) char smem[];
  constexpr int K = 2048, NK = 32;
  const int lin = blockIdx.x;
  const int wgid = (lin & 7) * 32 + (lin >> 3);
  const int bx = wgid >> 4, by = wgid & 15;       // col-strip per XCD
  const int brow = by * 128, bcol = bx * 192;
  const int t = threadIdx.x, lane = t & 63, w = t >> 6;
  const int wr = w >> 2, wc = w & 3;
  const int rr = lane & 15, rg = lane >> 4;

  char* Ab = smem;              // 3 x 16384
  char* Bb = smem + 49152;      // 3 x 24576

  auto stageA = [&](int kt) {
#pragma unroll
    for (int p = 0; p < 2; ++p) {
      const int idx = p * 512 + t;
      const int row = idx >> 3;
      const int cg = (idx & 7) ^ (row & 7);
      gload_lds16(A + (size_t)(brow + row) * K + kt * 64 + cg * 8,
                  Ab + (size_t)(kt % 3) * 16384 + (p * 512 + (t & ~63)) * 16);
    }
  };
  auto stageB = [&](int kt) {
#pragma unroll
    for (int p = 0; p < 3; ++p) {
      const int idx = p * 512 + t;
      const int row = idx >> 3;
      const int cg = (idx & 7) ^ (row & 7);
      gload_lds16(Bt + (size_t)(bcol + row) * K + kt * 64 + cg * 8,
                  Bb + (size_t)(kt % 3) * 24576 + (p * 512 + (t & ~63)) * 16);
    }
  };

  f32x4 acc[4][3];
#pragma unroll
  for (int i = 0; i < 4; ++i)
#pragma unroll
    for (int j = 0; j < 3; ++j) acc[i][j] = f32x4{0.f, 0.f, 0.f, 0.f};

  stageA(0); stageB(0); stageA(1); stageB(1);
  asm volatile("s_waitcnt vmcnt(5)" ::: "memory");
  __builtin_amdgcn_s_barrier();

  for (int kt = 0; kt < NK; ++kt) {
    const char* Ar = Ab + (size_t)(kt % 3) * 16384;
    const char* Br = Bb + (size_t)(kt % 3) * 24576;
#pragma unroll
    for (int ks = 0; ks < 2; ++ks) {
      bf16x8 af[4], bfr[3];
      const int c = ks * 4 + rg;
#pragma unroll
      for (int i = 0; i < 4; ++i) {
        const int row = wr * 64 + i * 16 + rr;
        af[i] = *reinterpret_cast<const bf16x8*>(Ar + row * 128 + ((c ^ (row & 7)) * 16));
      }
#pragma unroll
      for (int j = 0; j < 3; ++j) {
        const int row = wc * 48 + j * 16 + rr;
        bfr[j] = *reinterpret_cast<const bf16x8*>(Br + row * 128 + ((c ^ (row & 7)) * 16));
      }
      if (kt + 2 < NK) {
        if (ks == 0) stageA(kt + 2);
        else         stageB(kt + 2);
      }
      asm volatile("s_waitcnt lgkmcnt(0)" ::: "memory");
      __builtin_amdgcn_sched_barrier(0);
      __builtin_amdgcn_s_setprio(1);
#pragma unroll
      for (int i = 0; i < 4; ++i)
#pragma unroll
        for (int j = 0; j < 3; ++j)
          acc[i][j] = __builtin_amdgcn_mfma_f32_16x16x32_bf16(af[i], bfr[j], acc[i][j], 0, 0, 0);
      __builtin_amdgcn_s_setprio(0);
    }
    if (kt + 2 < NK)      asm volatile("s_waitcnt vmcnt(5)" ::: "memory");
    else if (kt + 1 < NK) asm volatile("s_waitcnt vmcnt(0)" ::: "memory");
    if (kt + 1 < NK) __builtin_amdgcn_s_barrier();
  }

#pragma unroll
  for (int j = 0; j < 3; ++j) {
    const int gcf = bcol + wc * 48 + j * 16;
    const int gc = gcf + rr;
    const float bv = bias[gc];
    if (gcf < 2048) {            // raw Q
#pragma unroll
      for (int i = 0; i < 4; ++i) {
        const int s0 = brow + wr * 64 + i * 16 + rg * 4;
#pragma unroll
        for (int r = 0; r < 4; ++r)
          qb[(size_t)(s0 + r) * 2048 + gc] = __float2bfloat16(acc[i][j][r] + bv);
      }
    } else if (gcf < 2560) {     // raw K
      const int kc = gc - 2048;
#pragma unroll
      for (int i = 0; i < 4; ++i) {
        const int s0 = brow + wr * 64 + i * 16 + rg * 4;
#pragma unroll
        for (int r = 0; r < 4; ++r)
          kb[(size_t)(s0 + r) * 512 + kc] = __float2bfloat16(acc[i][j][r] + bv);
      }
    } else {                     // V^T
      const int vcol = gc - 2560;
#pragma unroll
      for (int i = 0; i < 4; ++i) {
        ushort4 o;
        o.x = __builtin_bit_cast(unsigned short, __float2bfloat16(acc[i][j][0] + bv));
        o.y = __builtin_bit_cast(unsigned short, __float2bfloat16(acc[i][j][1] + bv));
        o.z = __builtin_bit_cast(unsigned short, __float2bfloat16(acc[i][j][2] + bv));
        o.w = __builtin_bit_cast(unsigned short, __float2bfloat16(acc[i][j][3] + bv));
        *reinterpret_cast<ushort4*>(
            &vt[(size_t)vcol * 2048 + brow + wr * 64 + i * 16 + rg * 4]) = o;
      }
    }
  }
}

// ---------------- GEMM2: BM=128 BN=128 BK=64, 8 waves (4M x 2N), 3-deep ----------------
__global__ __launch_bounds__(512, 1)
void gemm2_kernel(const bf16* __restrict__ A, const bf16* __restrict__ Bt,
                  const float* __restrict__ bias, float* __restrict__ C) {
  extern __shared__ __align__(16) char smem[];
  constexpr int K = 2048, NK = 32;
  const int lin = blockIdx.x;
  const int wgid = (lin & 7) * 32 + (lin >> 3);
  const int bx = wgid >> 4, by = wgid & 15;       // col-strip per XCD
  const int brow = by * 128, bcol = bx * 128;
  const int t = threadIdx.x, lane = t & 63, w = t >> 6;
  const int wr = w & 3, wc = w >> 2;              // 4 (M) x 2 (N)
  const int rr = lane & 15, rg = lane >> 4;

  char* Ab = smem;              // 3 x 16384
  char* Bb = smem + 49152;      // 3 x 16384

  auto stage = [&](int kt) {
#pragma unroll
    for (int p = 0; p < 2; ++p) {
      const int idx = p * 512 + t;
      const int row = idx >> 3;
      const int cg = (idx & 7) ^ (row & 7);
      gload_lds16(A + (size_t)(brow + row) * K + kt * 64 + cg * 8,
                  Ab + (size_t)(kt % 3) * 16384 + (p * 512 + (t & ~63)) * 16);
      gload_lds16(Bt + (size_t)(bcol + row) * K + kt * 64 + cg * 8,
                  Bb + (size_t)(kt % 3) * 16384 + (p * 512 + (t & ~63)) * 16);
    }
  };

  f32x4 acc[2][4];
#pragma unroll
  for (int i = 0; i < 2; ++i)
#pragma unroll
    for (int j = 0; j < 4; ++j) acc[i][j] = f32x4{0.f, 0.f, 0.f, 0.f};

  stage(0); stage(1);
  asm volatile("s_waitcnt vmcnt(4)" ::: "memory");
  __builtin_amdgcn_s_barrier();

  for (int kt = 0; kt < NK; ++kt) {
    const char* Ar = Ab + (size_t)(kt % 3) * 16384;
    const char* Br = Bb + (size_t)(kt % 3) * 16384;
#pragma unroll
    for (int ks = 0; ks < 2; ++ks) {
      bf16x8 af[2], bfr[4];
      const int c = ks * 4 + rg;
#pragma unroll
      for (int i = 0; i < 2; ++i) {
        const int row = wr * 32 + i * 16 + rr;
        af[i] = *reinterpret_cast<const bf16x8*>(Ar + row * 128 + ((c ^ (row & 7)) * 16));
      }
#pragma unroll
      for (int j = 0; j < 4; ++j) {
        const int row = wc * 64 + j * 16 + rr;
        bfr[j] = *reinterpret_cast<const bf16x8*>(Br + row * 128 + ((c ^ (row & 7)) * 16));
      }
      if (kt + 2 < NK && ks == 0) stage(kt + 2);
      asm volatile("s_waitcnt lgkmcnt(0)" ::: "memory");
      __builtin_amdgcn_sched_barrier(0);
      __builtin_amdgcn_s_setprio(1);
#pragma unroll
      for (int i = 0; i < 2; ++i)
#pragma unroll
        for (int j = 0; j < 4; ++j)
          acc[i][j] = __builtin_amdgcn_mfma_f32_16x16x32_bf16(af[i], bfr[j], acc[i][j], 0, 0, 0);
      __builtin_amdgcn_s_setprio(0);
    }
    if (kt + 2 < NK)      asm volatile("s_waitcnt vmcnt(4)" ::: "memory");
    else if (kt + 1 < NK) asm volatile("s_waitcnt vmcnt(0)" ::: "memory");
    if (kt + 1 < NK) __builtin_amdgcn_s_barrier();
  }

#pragma unroll
  for (int i = 0; i < 2; ++i)
#pragma unroll
    for (int j = 0; j < 4; ++j) {
      const int gc = bcol + wc * 64 + j * 16 + rr;
      const float bv = bias[gc];
      const int r0 = brow + wr * 32 + i * 16 + rg * 4;
#pragma unroll
      for (int r = 0; r < 4; ++r)
        C[(size_t)(r0 + r) * 2048 + gc] = acc[i][j][r] + bv;
    }
}

// ---------------- attention: grid (hk=8, qtile32=64), 4 waves = 4 q-heads ----------------
// R11 version (V LDS-staged, coalesced O). R12: launched TWICE (idempotent) to measure
// its true marginal duration via total-time delta.
__global__ __launch_bounds__(256, 2)
void attn_kernel(const bf16* __restrict__ Q, const bf16* __restrict__ Kb,
                 const bf16* __restrict__ Vt, const float* __restrict__ sinks,
                 const float* __restrict__ cosT, const float* __restrict__ sinT,
                 bf16* __restrict__ aout) {
  extern __shared__ __align__(16) char smem[];
  const int hk = blockIdx.x;
  const int q0 = blockIdx.y * 32;
  const int k0 = q0 - 128;                    // 160-key window
  const int t = threadIdx.x, w = t >> 6, lane = t & 63;
  const int cl = lane & 15, rg = lane >> 4;
  const int head = hk * 4 + w;

  char* Ks = smem;                            // [160 rows][8 x 16B] XOR-swizzled = 20480 B
  char* Vs = smem;                            // reuses K region after QK^T: [64 d][20 x 16B] rotated
  char* Ps = smem + 20480 + w * 12288;        // per-wave [32 rows][24 x 16B]

  // ---- cooperative K stage: 1280 chunks, 5 per thread (coalesced) ----
#pragma unroll
  for (int p = 0; p < 5; ++p) {
    const int idx = p * 256 + t;
    const int row = idx >> 3, c = idx & 7;
    int key = k0 + row;
    if (key < 0) key = 0;                     // garbage ok: masked below
    gload_lds16(Kb + (size_t)key * 512 + hk * 64 + ((c ^ (row & 7)) << 3),
                Ks + (size_t)(p * 256 + (t & ~63)) * 16);
  }

  // ---- Q fragments + fused RoPE (pair (d, d+32) = (frag0[e], frag1[e])) ----
  bf16x8 aq[2][2];
#pragma unroll
  for (int qf = 0; qf < 2; ++qf) {
    const int qrow = q0 + qf * 16 + cl;
    const bf16* qp = Q + (size_t)qrow * 2048 + head * 64 + rg * 8;
    const bf16x8 q1 = *reinterpret_cast<const bf16x8*>(qp);
    const bf16x8 q2 = *reinterpret_cast<const bf16x8*>(qp + 32);
    const float4 c0 = *reinterpret_cast<const float4*>(&cosT[qrow * 32 + rg * 8]);
    const float4 c1 = *reinterpret_cast<const float4*>(&cosT[qrow * 32 + rg * 8 + 4]);
    const float4 s0 = *reinterpret_cast<const float4*>(&sinT[qrow * 32 + rg * 8]);
    const float4 s1 = *reinterpret_cast<const float4*>(&sinT[qrow * 32 + rg * 8 + 4]);
    const float cs[8] = {c0.x, c0.y, c0.z, c0.w, c1.x, c1.y, c1.z, c1.w};
    const float sn[8] = {s0.x, s0.y, s0.z, s0.w, s1.x, s1.y, s1.z, s1.w};
#pragma unroll
    for (int e = 0; e < 8; ++e) {
      const float x1 = (float)q1[e], x2 = (float)q2[e];
      aq[qf][0][e] = (__bf16)(x1 * cs[e] - x2 * sn[e]);
      aq[qf][1][e] = (__bf16)(x2 * cs[e] + x1 * sn[e]);
    }
  }
  __syncthreads();   // K staged

  // ---- QK^T from LDS ----
  f32x4 acc[2][10];
#pragma unroll
  for (int qf = 0; qf < 2; ++qf)
#pragma unroll
    for (int nf = 0; nf < 10; ++nf) acc[qf][nf] = f32x4{0.f, 0.f, 0.f, 0.f};

#pragma unroll
  for (int nf = 0; nf < 10; ++nf) {
    const int row = nf * 16 + cl;
    bf16x8 bk[2];
#pragma unroll
    for (int ks = 0; ks < 2; ++ks) {
      const int chunk = ks * 4 + rg;
      bk[ks] = *reinterpret_cast<const bf16x8*>(
          Ks + row * 128 + ((chunk ^ (row & 7)) << 4));
    }
#pragma unroll
    for (int qf = 0; qf < 2; ++qf)
#pragma unroll
      for (int ks = 0; ks < 2; ++ks)
        acc[qf][nf] = __builtin_amdgcn_mfma_f32_16x16x32_bf16(aq[qf][ks], bk[ks], acc[qf][nf], 0, 0, 0);
  }

  __syncthreads();   // all waves done reading Ks -> region reusable for V

  // ---- cooperative V stage into (dead) K region: [64 d][20 chunks], rotation-permuted.
  {
    const bf16* vbase = Vt + (size_t)hk * 64 * 2048;
#pragma unroll
    for (int p = 0; p < 5; ++p) {
      const int idx = p * 256 + t;
      const int row = idx / 20;               // d in [0,64)
      const int slot = idx - row * 20;
      int src = slot - (row & 7);
      if (src < 0) src += 20;
      int key = k0 + src * 8;
      if (key < 0) key = 0;                   // P=0 there
      gload_lds16(vbase + (size_t)row * 2048 + key,
                  Vs + (size_t)(p * 256 + (t & ~63)) * 16);
    }
  }

  // ---- softmax (V staging drains underneath) ----
  const float sinkv = sinks[head];
  const float scale = 0.125f;  // 1/sqrt(64)
  const int cfloor = 128 - q0;  // key >= 0
#pragma unroll
  for (int qf = 0; qf < 2; ++qf)
#pragma unroll
    for (int r = 0; r < 4; ++r) {
      const int rowb = qf * 16 + rg * 4 + r;   // row within 32-tile
      int cmin = rowb;
      if (cfloor > cmin) cmin = cfloor;
      const int cmax = rowb + 128;
      float m = sinkv;
      float pv[10];
#pragma unroll
      for (int nf = 0; nf < 10; ++nf) {
        const int cc = nf * 16 + cl;
        float lv = (cc >= cmin && cc <= cmax) ? acc[qf][nf][r] * scale : -INFINITY;
        pv[nf] = lv;
        m = fmaxf(m, lv);
      }
#pragma unroll
      for (int off = 1; off < 16; off <<= 1)
        m = fmaxf(m, __shfl_xor(m, off, 64));
      float sum = 0.f;
#pragma unroll
      for (int nf = 0; nf < 10; ++nf) {
        const float p = __expf(pv[nf] - m);
        pv[nf] = p;
        sum += p;
      }
#pragma unroll
      for (int off = 1; off < 16; off <<= 1)
        sum += __shfl_xor(sum, off, 64);
      sum += __expf(sinkv - m);
      const float inv = 1.f / sum;
#pragma unroll
      for (int nf = 0; nf < 10; ++nf) {
        const int col = nf * 16 + cl;
        const int chunk = col >> 3;
        *reinterpret_cast<bf16*>(Ps + rowb * 384 + ((chunk ^ (rowb & 7)) << 4) + (cl & 7) * 2) =
            __float2bfloat16(pv[nf] * inv);
      }
    }

  // V staged (vmcnt) + P visible (lgkm); block-wide barrier before reading Vs
  asm volatile("s_waitcnt vmcnt(0) lgkmcnt(0)" ::: "memory");
  __builtin_amdgcn_sched_barrier(0);
  __syncthreads();

  // ---- PV: A = P (per-wave LDS), B = V (shared LDS) ----
  f32x4 oacc[2][4];
#pragma unroll
  for (int qf = 0; qf < 2; ++qf)
#pragma unroll
    for (int j = 0; j < 4; ++j) oacc[qf][j] = f32x4{0.f, 0.f, 0.f, 0.f};

#pragma unroll
  for (int ks = 0; ks < 5; ++ks) {
    bf16x8 pa[2];
#pragma unroll
    for (int qf = 0; qf < 2; ++qf) {
      const int row = qf * 16 + cl;
      const int chunk = ks * 4 + rg;
      pa[qf] = *reinterpret_cast<const bf16x8*>(
          Ps + row * 384 + ((chunk ^ (row & 7)) << 4));
    }
#pragma unroll
    for (int j = 0; j < 4; ++j) {
      const int d = j * 16 + cl;
      int slot = ks * 4 + rg + (d & 7);
      if (slot >= 20) slot -= 20;
      const bf16x8 bv = *reinterpret_cast<const bf16x8*>(Vs + d * 320 + slot * 16);
#pragma unroll
      for (int qf = 0; qf < 2; ++qf)
        oacc[qf][j] = __builtin_amdgcn_mfma_f32_16x16x32_bf16(pa[qf], bv, oacc[qf][j], 0, 0, 0);
    }
  }

  // ---- O -> per-wave P slab (dead), XOR-swizzled, then coalesced store ----
#pragma unroll
  for (int qf = 0; qf < 2; ++qf)
#pragma unroll
    for (int j = 0; j < 4; ++j)
#pragma unroll
      for (int r = 0; r < 4; ++r) {
        const int row = qf * 16 + rg * 4 + r;
        const int colb = (j * 16 + cl) * 2;   // byte in 128B row
        *reinterpret_cast<bf16*>(Ps + row * 384 + (colb ^ ((row & 7) << 4))) =
            __float2bfloat16(oacc[qf][j][r]);
      }
  __syncthreads();

  // block's out tile: [32 rows][256 cols] = rows of 512B, fully coalesced uint4 stores
#pragma unroll
  for (int p = 0; p < 4; ++p) {
    const int idx = p * 256 + t;
    const int row = idx >> 5;                 // 32 rows
    const int j16 = idx & 31;                 // 32 x 16B per row
    const int w2 = j16 >> 3, c8 = j16 & 7;
    const uint4 v = *reinterpret_cast<const uint4*>(
        smem + 20480 + w2 * 12288 + row * 384 + ((c8 * 16) ^ ((row & 7) << 4)));
    *reinterpret_cast<uint4*>(aout + (size_t)(q0 + row) * 2048 + hk * 256 + j16 * 8) = v;
  }
}

// ---------------- launch ----------------
extern "C" void kernel_launch(void* const* d_in, const int* in_sizes, int n_in,
                              void* d_out, int out_size, void* d_ws, size_t ws_size,
                              hipStream_t stream) {
  const float* x     = (const float*)d_in[0];
  const float* w1    = (const float*)d_in[1];
  const float* b1    = (const float*)d_in[2];
  const float* w2    = (const float*)d_in[3];
  const float* b2    = (const float*)d_in[4];
  const float* sinks = (const float*)d_in[5];
  const float* cosT  = (const float*)d_in[6];
  const float* sinT  = (const float*)d_in[7];
  float* out = (float*)d_out;

  char* ws = (char*)d_ws;
  bf16* xb   = (bf16*)(ws);                  // [2048][2048] 8 MB
  bf16* w1t  = (bf16*)(ws + 8388608);        // [3072][2048] 12 MB
  bf16* w2t  = (bf16*)(ws + 20971520);       // [2048][2048] 8 MB
  bf16* qbuf = (bf16*)(ws + 29360128);       // [2048][2048] 8 MB (raw Q; RoPE in attn)
  bf16* kbuf = (bf16*)(ws + 37748736);       // [2048][512]  2 MB (RoPE'd by rope_kernel)
  bf16* vt   = (bf16*)(ws + 39845888);       // [512][2048]  2 MB
  bf16* attn = (bf16*)(ws + 41943040);       // [2048][2048] 8 MB
  (void)in_sizes; (void)n_in; (void)out_size; (void)ws_size;

  prep_kernel<<<14336, 256, 0, stream>>>(x, w1, w2, xb, w1t, w2t);
  gemm1_kernel<<<256, 512, 122880, stream>>>(xb, w1t, b1, qbuf, kbuf, vt);
  rope_kernel<8, 5><<<256, 256, 0, stream>>>(kbuf, cosT, sinT);
  // R12 ATTRIBUTION: attn launched twice (idempotent). Marginal cost of the 2nd
  // launch = attn's true (warm) duration. Remove after reading the delta.
  attn_kernel<<<dim3(8, 64), 256, 69632, stream>>>(qbuf, kbuf, vt, sinks, cosT, sinT, attn);
  attn_kernel<<<dim3(8, 64), 256, 69632, stream>>>(qbuf, kbuf, vt, sinks, cosT, sinT, attn);
  gemm2_kernel<<<256, 512, 98304, stream>>>(attn, w2t, b2, out);
}

// Round 13
// 86.731 us; speedup vs baseline: 1.1367x; 1.1367x over previous
//
#include <hip/hip_runtime.h>
#include <hip/hip_bf16.h>
#include <cstdint>

typedef __hip_bfloat16 bf16;
typedef __attribute__((ext_vector_type(8))) __bf16 bf16x8;
typedef __attribute__((ext_vector_type(4))) float f32x4;

static __device__ __forceinline__ void gload_lds16(const void* g, void* l) {
  __builtin_amdgcn_global_load_lds(
      (const __attribute__((address_space(1))) uint32_t*)g,
      (__attribute__((address_space(3))) uint32_t*)l, 16, 0, 0);
}

// ---------------- merged prep: x->bf16 | w1^T->bf16 | w2^T->bf16 ----------------
__global__ __launch_bounds__(256)
void prep_kernel(const float* __restrict__ x, const float* __restrict__ w1,
                 const float* __restrict__ w2, bf16* __restrict__ xb,
                 bf16* __restrict__ w1t, bf16* __restrict__ w2t) {
  __shared__ float tile[32][33];
  const int lin = blockIdx.x;
  const int t = threadIdx.x;
  if (lin < 4096) {  // x conversion: 1M float4
    const int i = lin * 256 + t;
    const float4 v = reinterpret_cast<const float4*>(x)[i];
    ushort4 o;
    o.x = __builtin_bit_cast(unsigned short, __float2bfloat16(v.x));
    o.y = __builtin_bit_cast(unsigned short, __float2bfloat16(v.y));
    o.z = __builtin_bit_cast(unsigned short, __float2bfloat16(v.z));
    o.w = __builtin_bit_cast(unsigned short, __float2bfloat16(v.w));
    reinterpret_cast<ushort4*>(xb)[i] = o;
    return;
  }
  const float* in;
  bf16* out;
  int R, C, bx, by;
  if (lin < 10240) {
    const int tl = lin - 4096;
    in = w1; out = w1t; R = 2048; C = 3072; bx = tl % 96; by = tl / 96;
  } else {
    const int tl = lin - 10240;
    in = w2; out = w2t; R = 2048; C = 2048; bx = tl & 63; by = tl >> 6;
  }
  const int c0 = bx * 32, r0 = by * 32;
  const int tx = t & 31, ty = t >> 5;
#pragma unroll
  for (int i = 0; i < 4; ++i)
    tile[ty + i * 8][tx] = in[(size_t)(r0 + ty + i * 8) * C + c0 + tx];
  __syncthreads();
#pragma unroll
  for (int i = 0; i < 4; ++i)
    out[(size_t)(c0 + ty + i * 8) * R + r0 + tx] = __float2bfloat16(tile[tx][ty + i * 8]);
}

// ---------------- GEMM1: BM=64 BN=192 BK=64, 8 waves, 2-deep, 512 blocks (2/CU) ----------------
// R13: grid doubled so two blocks co-reside per CU; one block's vmcnt/barrier drain
// hides under the other's MFMA. A HBM traffic unchanged; extra B re-reads hit per-XCD L2.
__global__ __launch_bounds__(512, 4)
void gemm1_kernel(const bf16* __restrict__ A, const bf16* __restrict__ Bt,
                  const float* __restrict__ bias,
                  bf16* __restrict__ qb, bf16* __restrict__ kb, bf16* __restrict__ vt) {
  extern __shared__ __align__(16) char smem[];
  constexpr int K = 2048, NK = 32;
  const int lin = blockIdx.x;                      // 512 blocks, %8==0
  const int wgid = (lin & 7) * 64 + (lin >> 3);    // 64 consecutive per XCD
  const int bx = wgid >> 5, by = wgid & 31;        // col-strip per XCD (2 strips/XCD)
  const int brow = by * 64, bcol = bx * 192;
  const int t = threadIdx.x, lane = t & 63, w = t >> 6;
  const int wr = w >> 2, wc = w & 3;               // 2 (M) x 4 (N) waves of 32x48
  const int rr = lane & 15, rg = lane >> 4;

  char* Ab = smem;              // 2 x 8192  : [64 rows][8 x 16B]
  char* Bb = smem + 16384;      // 2 x 24576 : [192 rows][8 x 16B]

  auto stageA = [&](int kt) {
    const int row = t >> 3;
    const int cg = (t & 7) ^ (row & 7);
    gload_lds16(A + (size_t)(brow + row) * K + kt * 64 + cg * 8,
                Ab + (size_t)(kt & 1) * 8192 + (t & ~63) * 16);
  };
  auto stageB = [&](int kt) {
#pragma unroll
    for (int p = 0; p < 3; ++p) {
      const int idx = p * 512 + t;
      const int row = idx >> 3;
      const int cg = (idx & 7) ^ (row & 7);
      gload_lds16(Bt + (size_t)(bcol + row) * K + kt * 64 + cg * 8,
                  Bb + (size_t)(kt & 1) * 24576 + (p * 512 + (t & ~63)) * 16);
    }
  };

  f32x4 acc[2][3];
#pragma unroll
  for (int i = 0; i < 2; ++i)
#pragma unroll
    for (int j = 0; j < 3; ++j) acc[i][j] = f32x4{0.f, 0.f, 0.f, 0.f};

  stageA(0); stageB(0);
  asm volatile("s_waitcnt vmcnt(0)" ::: "memory");
  __builtin_amdgcn_s_barrier();

  for (int kt = 0; kt < NK; ++kt) {
    const char* Ar = Ab + (size_t)(kt & 1) * 8192;
    const char* Br = Bb + (size_t)(kt & 1) * 24576;
#pragma unroll
    for (int ks = 0; ks < 2; ++ks) {
      bf16x8 af[2], bfr[3];
      const int c = ks * 4 + rg;
#pragma unroll
      for (int i = 0; i < 2; ++i) {
        const int row = wr * 32 + i * 16 + rr;
        af[i] = *reinterpret_cast<const bf16x8*>(Ar + row * 128 + ((c ^ (row & 7)) * 16));
      }
#pragma unroll
      for (int j = 0; j < 3; ++j) {
        const int row = wc * 48 + j * 16 + rr;
        bfr[j] = *reinterpret_cast<const bf16x8*>(Br + row * 128 + ((c ^ (row & 7)) * 16));
      }
      if (ks == 0 && kt + 1 < NK) { stageA(kt + 1); stageB(kt + 1); }
      asm volatile("s_waitcnt lgkmcnt(0)" ::: "memory");
      __builtin_amdgcn_sched_barrier(0);
      __builtin_amdgcn_s_setprio(1);
#pragma unroll
      for (int i = 0; i < 2; ++i)
#pragma unroll
        for (int j = 0; j < 3; ++j)
          acc[i][j] = __builtin_amdgcn_mfma_f32_16x16x32_bf16(af[i], bfr[j], acc[i][j], 0, 0, 0);
      __builtin_amdgcn_s_setprio(0);
    }
    if (kt + 1 < NK) {
      asm volatile("s_waitcnt vmcnt(0)" ::: "memory");
      __builtin_amdgcn_s_barrier();
    }
  }

#pragma unroll
  for (int j = 0; j < 3; ++j) {
    const int gcf = bcol + wc * 48 + j * 16;
    const int gc = gcf + rr;
    const float bv = bias[gc];
    if (gcf < 2048) {            // raw Q
#pragma unroll
      for (int i = 0; i < 2; ++i) {
        const int s0 = brow + wr * 32 + i * 16 + rg * 4;
#pragma unroll
        for (int r = 0; r < 4; ++r)
          qb[(size_t)(s0 + r) * 2048 + gc] = __float2bfloat16(acc[i][j][r] + bv);
      }
    } else if (gcf < 2560) {     // raw K
      const int kc = gc - 2048;
#pragma unroll
      for (int i = 0; i < 2; ++i) {
        const int s0 = brow + wr * 32 + i * 16 + rg * 4;
#pragma unroll
        for (int r = 0; r < 4; ++r)
          kb[(size_t)(s0 + r) * 512 + kc] = __float2bfloat16(acc[i][j][r] + bv);
      }
    } else {                     // V^T
      const int vcol = gc - 2560;
#pragma unroll
      for (int i = 0; i < 2; ++i) {
        ushort4 o;
        o.x = __builtin_bit_cast(unsigned short, __float2bfloat16(acc[i][j][0] + bv));
        o.y = __builtin_bit_cast(unsigned short, __float2bfloat16(acc[i][j][1] + bv));
        o.z = __builtin_bit_cast(unsigned short, __float2bfloat16(acc[i][j][2] + bv));
        o.w = __builtin_bit_cast(unsigned short, __float2bfloat16(acc[i][j][3] + bv));
        *reinterpret_cast<ushort4*>(
            &vt[(size_t)vcol * 2048 + brow + wr * 32 + i * 16 + rg * 4]) = o;
      }
    }
  }
}

// ---------------- GEMM2: BM=128 BN=128 BK=64, 8 waves (4M x 2N), 3-deep (R10-proven) ----------------
__global__ __launch_bounds__(512, 1)
void gemm2_kernel(const bf16* __restrict__ A, const bf16* __restrict__ Bt,
                  const float* __restrict__ bias, float* __restrict__ C) {
  extern __shared__ __align__(16) char smem[];
  constexpr int K = 2048, NK = 32;
  const int lin = blockIdx.x;
  const int wgid = (lin & 7) * 32 + (lin >> 3);
  const int bx = wgid >> 4, by = wgid & 15;       // col-strip per XCD
  const int brow = by * 128, bcol = bx * 128;
  const int t = threadIdx.x, lane = t & 63, w = t >> 6;
  const int wr = w & 3, wc = w >> 2;              // 4 (M) x 2 (N)
  const int rr = lane & 15, rg = lane >> 4;

  char* Ab = smem;              // 3 x 16384
  char* Bb = smem + 49152;      // 3 x 16384

  auto stage = [&](int kt) {
#pragma unroll
    for (int p = 0; p < 2; ++p) {
      const int idx = p * 512 + t;
      const int row = idx >> 3;
      const int cg = (idx & 7) ^ (row & 7);
      gload_lds16(A + (size_t)(brow + row) * K + kt * 64 + cg * 8,
                  Ab + (size_t)(kt % 3) * 16384 + (p * 512 + (t & ~63)) * 16);
      gload_lds16(Bt + (size_t)(bcol + row) * K + kt * 64 + cg * 8,
                  Bb + (size_t)(kt % 3) * 16384 + (p * 512 + (t & ~63)) * 16);
    }
  };

  f32x4 acc[2][4];
#pragma unroll
  for (int i = 0; i < 2; ++i)
#pragma unroll
    for (int j = 0; j < 4; ++j) acc[i][j] = f32x4{0.f, 0.f, 0.f, 0.f};

  stage(0); stage(1);
  asm volatile("s_waitcnt vmcnt(4)" ::: "memory");
  __builtin_amdgcn_s_barrier();

  for (int kt = 0; kt < NK; ++kt) {
    const char* Ar = Ab + (size_t)(kt % 3) * 16384;
    const char* Br = Bb + (size_t)(kt % 3) * 16384;
#pragma unroll
    for (int ks = 0; ks < 2; ++ks) {
      bf16x8 af[2], bfr[4];
      const int c = ks * 4 + rg;
#pragma unroll
      for (int i = 0; i < 2; ++i) {
        const int row = wr * 32 + i * 16 + rr;
        af[i] = *reinterpret_cast<const bf16x8*>(Ar + row * 128 + ((c ^ (row & 7)) * 16));
      }
#pragma unroll
      for (int j = 0; j < 4; ++j) {
        const int row = wc * 64 + j * 16 + rr;
        bfr[j] = *reinterpret_cast<const bf16x8*>(Br + row * 128 + ((c ^ (row & 7)) * 16));
      }
      if (kt + 2 < NK && ks == 0) stage(kt + 2);
      asm volatile("s_waitcnt lgkmcnt(0)" ::: "memory");
      __builtin_amdgcn_sched_barrier(0);
      __builtin_amdgcn_s_setprio(1);
#pragma unroll
      for (int i = 0; i < 2; ++i)
#pragma unroll
        for (int j = 0; j < 4; ++j)
          acc[i][j] = __builtin_amdgcn_mfma_f32_16x16x32_bf16(af[i], bfr[j], acc[i][j], 0, 0, 0);
      __builtin_amdgcn_s_setprio(0);
    }
    if (kt + 2 < NK)      asm volatile("s_waitcnt vmcnt(4)" ::: "memory");
    else if (kt + 1 < NK) asm volatile("s_waitcnt vmcnt(0)" ::: "memory");
    if (kt + 1 < NK) __builtin_amdgcn_s_barrier();
  }

#pragma unroll
  for (int i = 0; i < 2; ++i)
#pragma unroll
    for (int j = 0; j < 4; ++j) {
      const int gc = bcol + wc * 64 + j * 16 + rr;
      const float bv = bias[gc];
      const int r0 = brow + wr * 32 + i * 16 + rg * 4;
#pragma unroll
      for (int r = 0; r < 4; ++r)
        C[(size_t)(r0 + r) * 2048 + gc] = acc[i][j][r] + bv;
    }
}

// ---------------- attention: grid (hk=8, qtile32=64), 4 waves = 4 q-heads ----------------
// R13: K-RoPE fused as in-LDS rotate pass (rope_kernel eliminated). V LDS-staged,
// coalesced O (R11). LDS 69632 (2 blk/CU).
__global__ __launch_bounds__(256, 2)
void attn_kernel(const bf16* __restrict__ Q, const bf16* __restrict__ Kb,
                 const bf16* __restrict__ Vt, const float* __restrict__ sinks,
                 const float* __restrict__ cosT, const float* __restrict__ sinT,
                 bf16* __restrict__ aout) {
  extern __shared__ __align__(16) char smem[];
  const int hk = blockIdx.x;
  const int q0 = blockIdx.y * 32;
  const int k0 = q0 - 128;                    // 160-key window
  const int t = threadIdx.x, w = t >> 6, lane = t & 63;
  const int cl = lane & 15, rg = lane >> 4;
  const int head = hk * 4 + w;

  char* Ks = smem;                            // [160 rows][8 x 16B] XOR-swizzled = 20480 B
  char* Vs = smem;                            // reuses K region after QK^T
  char* Ps = smem + 20480 + w * 12288;        // per-wave [32 rows][24 x 16B]

  // ---- cooperative K stage (raw, pre-RoPE): 1280 chunks ----
#pragma unroll
  for (int p = 0; p < 5; ++p) {
    const int idx = p * 256 + t;
    const int row = idx >> 3, c = idx & 7;
    int key = k0 + row;
    if (key < 0) key = 0;                     // garbage ok: masked below
    gload_lds16(Kb + (size_t)key * 512 + hk * 64 + ((c ^ (row & 7)) << 3),
                Ks + (size_t)(p * 256 + (t & ~63)) * 16);
  }

  // ---- Q fragments + fused RoPE (pair (d, d+32) = (frag0[e], frag1[e])) ----
  bf16x8 aq[2][2];
#pragma unroll
  for (int qf = 0; qf < 2; ++qf) {
    const int qrow = q0 + qf * 16 + cl;
    const bf16* qp = Q + (size_t)qrow * 2048 + head * 64 + rg * 8;
    const bf16x8 q1 = *reinterpret_cast<const bf16x8*>(qp);
    const bf16x8 q2 = *reinterpret_cast<const bf16x8*>(qp + 32);
    const float4 c0 = *reinterpret_cast<const float4*>(&cosT[qrow * 32 + rg * 8]);
    const float4 c1 = *reinterpret_cast<const float4*>(&cosT[qrow * 32 + rg * 8 + 4]);
    const float4 s0 = *reinterpret_cast<const float4*>(&sinT[qrow * 32 + rg * 8]);
    const float4 s1 = *reinterpret_cast<const float4*>(&sinT[qrow * 32 + rg * 8 + 4]);
    const float cs[8] = {c0.x, c0.y, c0.z, c0.w, c1.x, c1.y, c1.z, c1.w};
    const float sn[8] = {s0.x, s0.y, s0.z, s0.w, s1.x, s1.y, s1.z, s1.w};
#pragma unroll
    for (int e = 0; e < 8; ++e) {
      const float x1 = (float)q1[e], x2 = (float)q2[e];
      aq[qf][0][e] = (__bf16)(x1 * cs[e] - x2 * sn[e]);
      aq[qf][1][e] = (__bf16)(x2 * cs[e] + x1 * sn[e]);
    }
  }
  __syncthreads();   // K staged (compiler drains vmcnt before barrier)

  // ---- fused K-RoPE: rotate pairs (d, d+32) = swizzled chunks (c, c+4), in LDS ----
#pragma unroll
  for (int p = 0; p < 3; ++p) {
    const int task = p * 256 + t;
    if (task < 640) {                          // 160 rows x 4 chunk-pairs
      const int row = task >> 2, c = task & 3;
      int key = k0 + row;
      if (key < 0) key = 0;                    // garbage rows: rotation harmless, masked later
      char* base = Ks + row * 128;
      const int slotA = (c ^ (row & 7)) << 4;
      const int slotB = ((c + 4) ^ (row & 7)) << 4;
      bf16x8 v1 = *reinterpret_cast<bf16x8*>(base + slotA);
      bf16x8 v2 = *reinterpret_cast<bf16x8*>(base + slotB);
      const float4 ca0 = *reinterpret_cast<const float4*>(&cosT[key * 32 + c * 8]);
      const float4 ca1 = *reinterpret_cast<const float4*>(&cosT[key * 32 + c * 8 + 4]);
      const float4 sa0 = *reinterpret_cast<const float4*>(&sinT[key * 32 + c * 8]);
      const float4 sa1 = *reinterpret_cast<const float4*>(&sinT[key * 32 + c * 8 + 4]);
      const float cs[8] = {ca0.x, ca0.y, ca0.z, ca0.w, ca1.x, ca1.y, ca1.z, ca1.w};
      const float sn[8] = {sa0.x, sa0.y, sa0.z, sa0.w, sa1.x, sa1.y, sa1.z, sa1.w};
      bf16x8 o1, o2;
#pragma unroll
      for (int e = 0; e < 8; ++e) {
        const float x1 = (float)v1[e], x2 = (float)v2[e];
        o1[e] = (__bf16)(x1 * cs[e] - x2 * sn[e]);
        o2[e] = (__bf16)(x2 * cs[e] + x1 * sn[e]);
      }
      *reinterpret_cast<bf16x8*>(base + slotA) = o1;
      *reinterpret_cast<bf16x8*>(base + slotB) = o2;
    }
  }
  __syncthreads();   // rotated K visible to all waves

  // ---- QK^T from LDS ----
  f32x4 acc[2][10];
#pragma unroll
  for (int qf = 0; qf < 2; ++qf)
#pragma unroll
    for (int nf = 0; nf < 10; ++nf) acc[qf][nf] = f32x4{0.f, 0.f, 0.f, 0.f};

#pragma unroll
  for (int nf = 0; nf < 10; ++nf) {
    const int row = nf * 16 + cl;
    bf16x8 bk[2];
#pragma unroll
    for (int ks = 0; ks < 2; ++ks) {
      const int chunk = ks * 4 + rg;
      bk[ks] = *reinterpret_cast<const bf16x8*>(
          Ks + row * 128 + ((chunk ^ (row & 7)) << 4));
    }
#pragma unroll
    for (int qf = 0; qf < 2; ++qf)
#pragma unroll
      for (int ks = 0; ks < 2; ++ks)
        acc[qf][nf] = __builtin_amdgcn_mfma_f32_16x16x32_bf16(aq[qf][ks], bk[ks], acc[qf][nf], 0, 0, 0);
  }

  __syncthreads();   // all waves done reading Ks -> region reusable for V

  // ---- cooperative V stage into (dead) K region: [64 d][20 chunks], rotation-permuted ----
  {
    const bf16* vbase = Vt + (size_t)hk * 64 * 2048;
#pragma unroll
    for (int p = 0; p < 5; ++p) {
      const int idx = p * 256 + t;
      const int row = idx / 20;               // d in [0,64)
      const int slot = idx - row * 20;
      int src = slot - (row & 7);
      if (src < 0) src += 20;
      int key = k0 + src * 8;
      if (key < 0) key = 0;                   // P=0 there
      gload_lds16(vbase + (size_t)row * 2048 + key,
                  Vs + (size_t)(p * 256 + (t & ~63)) * 16);
    }
  }

  // ---- softmax (V staging drains underneath) ----
  const float sinkv = sinks[head];
  const float scale = 0.125f;  // 1/sqrt(64)
  const int cfloor = 128 - q0;  // key >= 0
#pragma unroll
  for (int qf = 0; qf < 2; ++qf)
#pragma unroll
    for (int r = 0; r < 4; ++r) {
      const int rowb = qf * 16 + rg * 4 + r;   // row within 32-tile
      int cmin = rowb;
      if (cfloor > cmin) cmin = cfloor;
      const int cmax = rowb + 128;
      float m = sinkv;
      float pv[10];
#pragma unroll
      for (int nf = 0; nf < 10; ++nf) {
        const int cc = nf * 16 + cl;
        float lv = (cc >= cmin && cc <= cmax) ? acc[qf][nf][r] * scale : -INFINITY;
        pv[nf] = lv;
        m = fmaxf(m, lv);
      }
#pragma unroll
      for (int off = 1; off < 16; off <<= 1)
        m = fmaxf(m, __shfl_xor(m, off, 64));
      float sum = 0.f;
#pragma unroll
      for (int nf = 0; nf < 10; ++nf) {
        const float p = __expf(pv[nf] - m);
        pv[nf] = p;
        sum += p;
      }
#pragma unroll
      for (int off = 1; off < 16; off <<= 1)
        sum += __shfl_xor(sum, off, 64);
      sum += __expf(sinkv - m);
      const float inv = 1.f / sum;
#pragma unroll
      for (int nf = 0; nf < 10; ++nf) {
        const int col = nf * 16 + cl;
        const int chunk = col >> 3;
        *reinterpret_cast<bf16*>(Ps + rowb * 384 + ((chunk ^ (rowb & 7)) << 4) + (cl & 7) * 2) =
            __float2bfloat16(pv[nf] * inv);
      }
    }

  // V staged (vmcnt) + P visible (lgkm); block-wide barrier before reading Vs
  asm volatile("s_waitcnt vmcnt(0) lgkmcnt(0)" ::: "memory");
  __builtin_amdgcn_sched_barrier(0);
  __syncthreads();

  // ---- PV: A = P (per-wave LDS), B = V (shared LDS) ----
  f32x4 oacc[2][4];
#pragma unroll
  for (int qf = 0; qf < 2; ++qf)
#pragma unroll
    for (int j = 0; j < 4; ++j) oacc[qf][j] = f32x4{0.f, 0.f, 0.f, 0.f};

#pragma unroll
  for (int ks = 0; ks < 5; ++ks) {
    bf16x8 pa[2];
#pragma unroll
    for (int qf = 0; qf < 2; ++qf) {
      const int row = qf * 16 + cl;
      const int chunk = ks * 4 + rg;
      pa[qf] = *reinterpret_cast<const bf16x8*>(
          Ps + row * 384 + ((chunk ^ (row & 7)) << 4));
    }
#pragma unroll
    for (int j = 0; j < 4; ++j) {
      const int d = j * 16 + cl;
      int slot = ks * 4 + rg + (d & 7);
      if (slot >= 20) slot -= 20;
      const bf16x8 bv = *reinterpret_cast<const bf16x8*>(Vs + d * 320 + slot * 16);
#pragma unroll
      for (int qf = 0; qf < 2; ++qf)
        oacc[qf][j] = __builtin_amdgcn_mfma_f32_16x16x32_bf16(pa[qf], bv, oacc[qf][j], 0, 0, 0);
    }
  }

  // ---- O -> per-wave P slab (dead), XOR-swizzled, then coalesced store ----
#pragma unroll
  for (int qf = 0; qf < 2; ++qf)
#pragma unroll
    for (int j = 0; j < 4; ++j)
#pragma unroll
      for (int r = 0; r < 4; ++r) {
        const int row = qf * 16 + rg * 4 + r;
        const int colb = (j * 16 + cl) * 2;   // byte in 128B row
        *reinterpret_cast<bf16*>(Ps + row * 384 + (colb ^ ((row & 7) << 4))) =
            __float2bfloat16(oacc[qf][j][r]);
      }
  __syncthreads();

  // block's out tile: [32 rows][256 cols] = rows of 512B, fully coalesced uint4 stores
#pragma unroll
  for (int p = 0; p < 4; ++p) {
    const int idx = p * 256 + t;
    const int row = idx >> 5;                 // 32 rows
    const int j16 = idx & 31;                 // 32 x 16B per row
    const int w2 = j16 >> 3, c8 = j16 & 7;
    const uint4 v = *reinterpret_cast<const uint4*>(
        smem + 20480 + w2 * 12288 + row * 384 + ((c8 * 16) ^ ((row & 7) << 4)));
    *reinterpret_cast<uint4*>(aout + (size_t)(q0 + row) * 2048 + hk * 256 + j16 * 8) = v;
  }
}

// ---------------- launch ----------------
extern "C" void kernel_launch(void* const* d_in, const int* in_sizes, int n_in,
                              void* d_out, int out_size, void* d_ws, size_t ws_size,
                              hipStream_t stream) {
  const float* x     = (const float*)d_in[0];
  const float* w1    = (const float*)d_in[1];
  const float* b1    = (const float*)d_in[2];
  const float* w2    = (const float*)d_in[3];
  const float* b2    = (const float*)d_in[4];
  const float* sinks = (const float*)d_in[5];
  const float* cosT  = (const float*)d_in[6];
  const float* sinT  = (const float*)d_in[7];
  float* out = (float*)d_out;

  char* ws = (char*)d_ws;
  bf16* xb   = (bf16*)(ws);                  // [2048][2048] 8 MB
  bf16* w1t  = (bf16*)(ws + 8388608);        // [3072][2048] 12 MB
  bf16* w2t  = (bf16*)(ws + 20971520);       // [2048][2048] 8 MB
  bf16* qbuf = (bf16*)(ws + 29360128);       // [2048][2048] 8 MB (raw Q; RoPE in attn)
  bf16* kbuf = (bf16*)(ws + 37748736);       // [2048][512]  2 MB (raw K; RoPE in attn)
  bf16* vt   = (bf16*)(ws + 39845888);       // [512][2048]  2 MB
  bf16* attn = (bf16*)(ws + 41943040);       // [2048][2048] 8 MB
  (void)in_sizes; (void)n_in; (void)out_size; (void)ws_size;

  prep_kernel<<<14336, 256, 0, stream>>>(x, w1, w2, xb, w1t, w2t);
  gemm1_kernel<<<512, 512, 65536, stream>>>(xb, w1t, b1, qbuf, kbuf, vt);
  attn_kernel<<<dim3(8, 64), 256, 69632, stream>>>(qbuf, kbuf, vt, sinks, cosT, sinT, attn);
  gemm2_kernel<<<256, 512, 98304, stream>>>(attn, w2t, b2, out);
}

// Round 14
// 84.694 us; speedup vs baseline: 1.1640x; 1.0241x over previous
//
#include <hip/hip_runtime.h>
#include <hip/hip_bf16.h>
#include <cstdint>

typedef __hip_bfloat16 bf16;
typedef __attribute__((ext_vector_type(8))) __bf16 bf16x8;
typedef __attribute__((ext_vector_type(4))) float f32x4;

static __device__ __forceinline__ void gload_lds16(const void* g, void* l) {
  __builtin_amdgcn_global_load_lds(
      (const __attribute__((address_space(1))) uint32_t*)g,
      (__attribute__((address_space(3))) uint32_t*)l, 16, 0, 0);
}

// ---------------- merged prep: x->bf16 | w1^T->bf16 | w2^T->bf16 ----------------
__global__ __launch_bounds__(256)
void prep_kernel(const float* __restrict__ x, const float* __restrict__ w1,
                 const float* __restrict__ w2, bf16* __restrict__ xb,
                 bf16* __restrict__ w1t, bf16* __restrict__ w2t) {
  __shared__ float tile[32][33];
  const int lin = blockIdx.x;
  const int t = threadIdx.x;
  if (lin < 4096) {  // x conversion: 1M float4
    const int i = lin * 256 + t;
    const float4 v = reinterpret_cast<const float4*>(x)[i];
    ushort4 o;
    o.x = __builtin_bit_cast(unsigned short, __float2bfloat16(v.x));
    o.y = __builtin_bit_cast(unsigned short, __float2bfloat16(v.y));
    o.z = __builtin_bit_cast(unsigned short, __float2bfloat16(v.z));
    o.w = __builtin_bit_cast(unsigned short, __float2bfloat16(v.w));
    reinterpret_cast<ushort4*>(xb)[i] = o;
    return;
  }
  const float* in;
  bf16* out;
  int R, C, bx, by;
  if (lin < 10240) {
    const int tl = lin - 4096;
    in = w1; out = w1t; R = 2048; C = 3072; bx = tl % 96; by = tl / 96;
  } else {
    const int tl = lin - 10240;
    in = w2; out = w2t; R = 2048; C = 2048; bx = tl & 63; by = tl >> 6;
  }
  const int c0 = bx * 32, r0 = by * 32;
  const int tx = t & 31, ty = t >> 5;
#pragma unroll
  for (int i = 0; i < 4; ++i)
    tile[ty + i * 8][tx] = in[(size_t)(r0 + ty + i * 8) * C + c0 + tx];
  __syncthreads();
#pragma unroll
  for (int i = 0; i < 4; ++i)
    out[(size_t)(c0 + ty + i * 8) * R + r0 + tx] = __float2bfloat16(tile[tx][ty + i * 8]);
}

// ---------------- GEMM1: BM=128 BN=192 BK=64, 8 waves, 3-deep (R10-proven, reverted) ----------------
__global__ __launch_bounds__(512, 1)
void gemm1_kernel(const bf16* __restrict__ A, const bf16* __restrict__ Bt,
                  const float* __restrict__ bias,
                  bf16* __restrict__ qb, bf16* __restrict__ kb, bf16* __restrict__ vt) {
  extern __shared__ __align__(16) char smem[];
  constexpr int K = 2048, NK = 32;
  const int lin = blockIdx.x;
  const int wgid = (lin & 7) * 32 + (lin >> 3);
  const int bx = wgid >> 4, by = wgid & 15;       // col-strip per XCD
  const int brow = by * 128, bcol = bx * 192;
  const int t = threadIdx.x, lane = t & 63, w = t >> 6;
  const int wr = w >> 2, wc = w & 3;
  const int rr = lane & 15, rg = lane >> 4;

  char* Ab = smem;              // 3 x 16384
  char* Bb = smem + 49152;      // 3 x 24576

  auto stageA = [&](int kt) {
#pragma unroll
    for (int p = 0; p < 2; ++p) {
      const int idx = p * 512 + t;
      const int row = idx >> 3;
      const int cg = (idx & 7) ^ (row & 7);
      gload_lds16(A + (size_t)(brow + row) * K + kt * 64 + cg * 8,
                  Ab + (size_t)(kt % 3) * 16384 + (p * 512 + (t & ~63)) * 16);
    }
  };
  auto stageB = [&](int kt) {
#pragma unroll
    for (int p = 0; p < 3; ++p) {
      const int idx = p * 512 + t;
      const int row = idx >> 3;
      const int cg = (idx & 7) ^ (row & 7);
      gload_lds16(Bt + (size_t)(bcol + row) * K + kt * 64 + cg * 8,
                  Bb + (size_t)(kt % 3) * 24576 + (p * 512 + (t & ~63)) * 16);
    }
  };

  f32x4 acc[4][3];
#pragma unroll
  for (int i = 0; i < 4; ++i)
#pragma unroll
    for (int j = 0; j < 3; ++j) acc[i][j] = f32x4{0.f, 0.f, 0.f, 0.f};

  stageA(0); stageB(0); stageA(1); stageB(1);
  asm volatile("s_waitcnt vmcnt(5)" ::: "memory");
  __builtin_amdgcn_s_barrier();

  for (int kt = 0; kt < NK; ++kt) {
    const char* Ar = Ab + (size_t)(kt % 3) * 16384;
    const char* Br = Bb + (size_t)(kt % 3) * 24576;
#pragma unroll
    for (int ks = 0; ks < 2; ++ks) {
      bf16x8 af[4], bfr[3];
      const int c = ks * 4 + rg;
#pragma unroll
      for (int i = 0; i < 4; ++i) {
        const int row = wr * 64 + i * 16 + rr;
        af[i] = *reinterpret_cast<const bf16x8*>(Ar + row * 128 + ((c ^ (row & 7)) * 16));
      }
#pragma unroll
      for (int j = 0; j < 3; ++j) {
        const int row = wc * 48 + j * 16 + rr;
        bfr[j] = *reinterpret_cast<const bf16x8*>(Br + row * 128 + ((c ^ (row & 7)) * 16));
      }
      if (kt + 2 < NK) {
        if (ks == 0) stageA(kt + 2);
        else         stageB(kt + 2);
      }
      asm volatile("s_waitcnt lgkmcnt(0)" ::: "memory");
      __builtin_amdgcn_sched_barrier(0);
      __builtin_amdgcn_s_setprio(1);
#pragma unroll
      for (int i = 0; i < 4; ++i)
#pragma unroll
        for (int j = 0; j < 3; ++j)
          acc[i][j] = __builtin_amdgcn_mfma_f32_16x16x32_bf16(af[i], bfr[j], acc[i][j], 0, 0, 0);
      __builtin_amdgcn_s_setprio(0);
    }
    if (kt + 2 < NK)      asm volatile("s_waitcnt vmcnt(5)" ::: "memory");
    else if (kt + 1 < NK) asm volatile("s_waitcnt vmcnt(0)" ::: "memory");
    if (kt + 1 < NK) __builtin_amdgcn_s_barrier();
  }

#pragma unroll
  for (int j = 0; j < 3; ++j) {
    const int gcf = bcol + wc * 48 + j * 16;
    const int gc = gcf + rr;
    const float bv = bias[gc];
    if (gcf < 2048) {            // raw Q
#pragma unroll
      for (int i = 0; i < 4; ++i) {
        const int s0 = brow + wr * 64 + i * 16 + rg * 4;
#pragma unroll
        for (int r = 0; r < 4; ++r)
          qb[(size_t)(s0 + r) * 2048 + gc] = __float2bfloat16(acc[i][j][r] + bv);
      }
    } else if (gcf < 2560) {     // raw K
      const int kc = gc - 2048;
#pragma unroll
      for (int i = 0; i < 4; ++i) {
        const int s0 = brow + wr * 64 + i * 16 + rg * 4;
#pragma unroll
        for (int r = 0; r < 4; ++r)
          kb[(size_t)(s0 + r) * 512 + kc] = __float2bfloat16(acc[i][j][r] + bv);
      }
    } else {                     // V^T
      const int vcol = gc - 2560;
#pragma unroll
      for (int i = 0; i < 4; ++i) {
        ushort4 o;
        o.x = __builtin_bit_cast(unsigned short, __float2bfloat16(acc[i][j][0] + bv));
        o.y = __builtin_bit_cast(unsigned short, __float2bfloat16(acc[i][j][1] + bv));
        o.z = __builtin_bit_cast(unsigned short, __float2bfloat16(acc[i][j][2] + bv));
        o.w = __builtin_bit_cast(unsigned short, __float2bfloat16(acc[i][j][3] + bv));
        *reinterpret_cast<ushort4*>(
            &vt[(size_t)vcol * 2048 + brow + wr * 64 + i * 16 + rg * 4]) = o;
      }
    }
  }
}

// ---------------- GEMM2: BM=128 BN=128 BK=64, 8 waves (4M x 2N), 3-deep (R10-proven) ----------------
__global__ __launch_bounds__(512, 1)
void gemm2_kernel(const bf16* __restrict__ A, const bf16* __restrict__ Bt,
                  const float* __restrict__ bias, float* __restrict__ C) {
  extern __shared__ __align__(16) char smem[];
  constexpr int K = 2048, NK = 32;
  const int lin = blockIdx.x;
  const int wgid = (lin & 7) * 32 + (lin >> 3);
  const int bx = wgid >> 4, by = wgid & 15;       // col-strip per XCD
  const int brow = by * 128, bcol = bx * 128;
  const int t = threadIdx.x, lane = t & 63, w = t >> 6;
  const int wr = w & 3, wc = w >> 2;              // 4 (M) x 2 (N)
  const int rr = lane & 15, rg = lane >> 4;

  char* Ab = smem;              // 3 x 16384
  char* Bb = smem + 49152;      // 3 x 16384

  auto stage = [&](int kt) {
#pragma unroll
    for (int p = 0; p < 2; ++p) {
      const int idx = p * 512 + t;
      const int row = idx >> 3;
      const int cg = (idx & 7) ^ (row & 7);
      gload_lds16(A + (size_t)(brow + row) * K + kt * 64 + cg * 8,
                  Ab + (size_t)(kt % 3) * 16384 + (p * 512 + (t & ~63)) * 16);
      gload_lds16(Bt + (size_t)(bcol + row) * K + kt * 64 + cg * 8,
                  Bb + (size_t)(kt % 3) * 16384 + (p * 512 + (t & ~63)) * 16);
    }
  };

  f32x4 acc[2][4];
#pragma unroll
  for (int i = 0; i < 2; ++i)
#pragma unroll
    for (int j = 0; j < 4; ++j) acc[i][j] = f32x4{0.f, 0.f, 0.f, 0.f};

  stage(0); stage(1);
  asm volatile("s_waitcnt vmcnt(4)" ::: "memory");
  __builtin_amdgcn_s_barrier();

  for (int kt = 0; kt < NK; ++kt) {
    const char* Ar = Ab + (size_t)(kt % 3) * 16384;
    const char* Br = Bb + (size_t)(kt % 3) * 16384;
#pragma unroll
    for (int ks = 0; ks < 2; ++ks) {
      bf16x8 af[2], bfr[4];
      const int c = ks * 4 + rg;
#pragma unroll
      for (int i = 0; i < 2; ++i) {
        const int row = wr * 32 + i * 16 + rr;
        af[i] = *reinterpret_cast<const bf16x8*>(Ar + row * 128 + ((c ^ (row & 7)) * 16));
      }
#pragma unroll
      for (int j = 0; j < 4; ++j) {
        const int row = wc * 64 + j * 16 + rr;
        bfr[j] = *reinterpret_cast<const bf16x8*>(Br + row * 128 + ((c ^ (row & 7)) * 16));
      }
      if (kt + 2 < NK && ks == 0) stage(kt + 2);
      asm volatile("s_waitcnt lgkmcnt(0)" ::: "memory");
      __builtin_amdgcn_sched_barrier(0);
      __builtin_amdgcn_s_setprio(1);
#pragma unroll
      for (int i = 0; i < 2; ++i)
#pragma unroll
        for (int j = 0; j < 4; ++j)
          acc[i][j] = __builtin_amdgcn_mfma_f32_16x16x32_bf16(af[i], bfr[j], acc[i][j], 0, 0, 0);
      __builtin_amdgcn_s_setprio(0);
    }
    if (kt + 2 < NK)      asm volatile("s_waitcnt vmcnt(4)" ::: "memory");
    else if (kt + 1 < NK) asm volatile("s_waitcnt vmcnt(0)" ::: "memory");
    if (kt + 1 < NK) __builtin_amdgcn_s_barrier();
  }

#pragma unroll
  for (int i = 0; i < 2; ++i)
#pragma unroll
    for (int j = 0; j < 4; ++j) {
      const int gc = bcol + wc * 64 + j * 16 + rr;
      const float bv = bias[gc];
      const int r0 = brow + wr * 32 + i * 16 + rg * 4;
#pragma unroll
      for (int r = 0; r < 4; ++r)
        C[(size_t)(r0 + r) * 2048 + gc] = acc[i][j][r] + bv;
    }
}

// ---------------- attention: grid (hk=8, qtile32=64), 4 waves = 4 q-heads ----------------
// R13 version kept: K-RoPE fused as in-LDS rotate pass; V LDS-staged; coalesced O.
__global__ __launch_bounds__(256, 2)
void attn_kernel(const bf16* __restrict__ Q, const bf16* __restrict__ Kb,
                 const bf16* __restrict__ Vt, const float* __restrict__ sinks,
                 const float* __restrict__ cosT, const float* __restrict__ sinT,
                 bf16* __restrict__ aout) {
  extern __shared__ __align__(16) char smem[];
  const int hk = blockIdx.x;
  const int q0 = blockIdx.y * 32;
  const int k0 = q0 - 128;                    // 160-key window
  const int t = threadIdx.x, w = t >> 6, lane = t & 63;
  const int cl = lane & 15, rg = lane >> 4;
  const int head = hk * 4 + w;

  char* Ks = smem;                            // [160 rows][8 x 16B] XOR-swizzled = 20480 B
  char* Vs = smem;                            // reuses K region after QK^T
  char* Ps = smem + 20480 + w * 12288;        // per-wave [32 rows][24 x 16B]

  // ---- cooperative K stage (raw, pre-RoPE): 1280 chunks ----
#pragma unroll
  for (int p = 0; p < 5; ++p) {
    const int idx = p * 256 + t;
    const int row = idx >> 3, c = idx & 7;
    int key = k0 + row;
    if (key < 0) key = 0;                     // garbage ok: masked below
    gload_lds16(Kb + (size_t)key * 512 + hk * 64 + ((c ^ (row & 7)) << 3),
                Ks + (size_t)(p * 256 + (t & ~63)) * 16);
  }

  // ---- Q fragments + fused RoPE (pair (d, d+32) = (frag0[e], frag1[e])) ----
  bf16x8 aq[2][2];
#pragma unroll
  for (int qf = 0; qf < 2; ++qf) {
    const int qrow = q0 + qf * 16 + cl;
    const bf16* qp = Q + (size_t)qrow * 2048 + head * 64 + rg * 8;
    const bf16x8 q1 = *reinterpret_cast<const bf16x8*>(qp);
    const bf16x8 q2 = *reinterpret_cast<const bf16x8*>(qp + 32);
    const float4 c0 = *reinterpret_cast<const float4*>(&cosT[qrow * 32 + rg * 8]);
    const float4 c1 = *reinterpret_cast<const float4*>(&cosT[qrow * 32 + rg * 8 + 4]);
    const float4 s0 = *reinterpret_cast<const float4*>(&sinT[qrow * 32 + rg * 8]);
    const float4 s1 = *reinterpret_cast<const float4*>(&sinT[qrow * 32 + rg * 8 + 4]);
    const float cs[8] = {c0.x, c0.y, c0.z, c0.w, c1.x, c1.y, c1.z, c1.w};
    const float sn[8] = {s0.x, s0.y, s0.z, s0.w, s1.x, s1.y, s1.z, s1.w};
#pragma unroll
    for (int e = 0; e < 8; ++e) {
      const float x1 = (float)q1[e], x2 = (float)q2[e];
      aq[qf][0][e] = (__bf16)(x1 * cs[e] - x2 * sn[e]);
      aq[qf][1][e] = (__bf16)(x2 * cs[e] + x1 * sn[e]);
    }
  }
  __syncthreads();   // K staged (compiler drains vmcnt before barrier)

  // ---- fused K-RoPE: rotate pairs (d, d+32) = swizzled chunks (c, c+4), in LDS ----
#pragma unroll
  for (int p = 0; p < 3; ++p) {
    const int task = p * 256 + t;
    if (task < 640) {                          // 160 rows x 4 chunk-pairs
      const int row = task >> 2, c = task & 3;
      int key = k0 + row;
      if (key < 0) key = 0;                    // garbage rows: rotation harmless, masked later
      char* base = Ks + row * 128;
      const int slotA = (c ^ (row & 7)) << 4;
      const int slotB = ((c + 4) ^ (row & 7)) << 4;
      bf16x8 v1 = *reinterpret_cast<bf16x8*>(base + slotA);
      bf16x8 v2 = *reinterpret_cast<bf16x8*>(base + slotB);
      const float4 ca0 = *reinterpret_cast<const float4*>(&cosT[key * 32 + c * 8]);
      const float4 ca1 = *reinterpret_cast<const float4*>(&cosT[key * 32 + c * 8 + 4]);
      const float4 sa0 = *reinterpret_cast<const float4*>(&sinT[key * 32 + c * 8]);
      const float4 sa1 = *reinterpret_cast<const float4*>(&sinT[key * 32 + c * 8 + 4]);
      const float cs[8] = {ca0.x, ca0.y, ca0.z, ca0.w, ca1.x, ca1.y, ca1.z, ca1.w};
      const float sn[8] = {sa0.x, sa0.y, sa0.z, sa0.w, sa1.x, sa1.y, sa1.z, sa1.w};
      bf16x8 o1, o2;
#pragma unroll
      for (int e = 0; e < 8; ++e) {
        const float x1 = (float)v1[e], x2 = (float)v2[e];
        o1[e] = (__bf16)(x1 * cs[e] - x2 * sn[e]);
        o2[e] = (__bf16)(x2 * cs[e] + x1 * sn[e]);
      }
      *reinterpret_cast<bf16x8*>(base + slotA) = o1;
      *reinterpret_cast<bf16x8*>(base + slotB) = o2;
    }
  }
  __syncthreads();   // rotated K visible to all waves

  // ---- QK^T from LDS ----
  f32x4 acc[2][10];
#pragma unroll
  for (int qf = 0; qf < 2; ++qf)
#pragma unroll
    for (int nf = 0; nf < 10; ++nf) acc[qf][nf] = f32x4{0.f, 0.f, 0.f, 0.f};

#pragma unroll
  for (int nf = 0; nf < 10; ++nf) {
    const int row = nf * 16 + cl;
    bf16x8 bk[2];
#pragma unroll
    for (int ks = 0; ks < 2; ++ks) {
      const int chunk = ks * 4 + rg;
      bk[ks] = *reinterpret_cast<const bf16x8*>(
          Ks + row * 128 + ((chunk ^ (row & 7)) << 4));
    }
#pragma unroll
    for (int qf = 0; qf < 2; ++qf)
#pragma unroll
      for (int ks = 0; ks < 2; ++ks)
        acc[qf][nf] = __builtin_amdgcn_mfma_f32_16x16x32_bf16(aq[qf][ks], bk[ks], acc[qf][nf], 0, 0, 0);
  }

  __syncthreads();   // all waves done reading Ks -> region reusable for V

  // ---- cooperative V stage into (dead) K region: [64 d][20 chunks], rotation-permuted ----
  {
    const bf16* vbase = Vt + (size_t)hk * 64 * 2048;
#pragma unroll
    for (int p = 0; p < 5; ++p) {
      const int idx = p * 256 + t;
      const int row = idx / 20;               // d in [0,64)
      const int slot = idx - row * 20;
      int src = slot - (row & 7);
      if (src < 0) src += 20;
      int key = k0 + src * 8;
      if (key < 0) key = 0;                   // P=0 there
      gload_lds16(vbase + (size_t)row * 2048 + key,
                  Vs + (size_t)(p * 256 + (t & ~63)) * 16);
    }
  }

  // ---- softmax (V staging drains underneath) ----
  const float sinkv = sinks[head];
  const float scale = 0.125f;  // 1/sqrt(64)
  const int cfloor = 128 - q0;  // key >= 0
#pragma unroll
  for (int qf = 0; qf < 2; ++qf)
#pragma unroll
    for (int r = 0; r < 4; ++r) {
      const int rowb = qf * 16 + rg * 4 + r;   // row within 32-tile
      int cmin = rowb;
      if (cfloor > cmin) cmin = cfloor;
      const int cmax = rowb + 128;
      float m = sinkv;
      float pv[10];
#pragma unroll
      for (int nf = 0; nf < 10; ++nf) {
        const int cc = nf * 16 + cl;
        float lv = (cc >= cmin && cc <= cmax) ? acc[qf][nf][r] * scale : -INFINITY;
        pv[nf] = lv;
        m = fmaxf(m, lv);
      }
#pragma unroll
      for (int off = 1; off < 16; off <<= 1)
        m = fmaxf(m, __shfl_xor(m, off, 64));
      float sum = 0.f;
#pragma unroll
      for (int nf = 0; nf < 10; ++nf) {
        const float p = __expf(pv[nf] - m);
        pv[nf] = p;
        sum += p;
      }
#pragma unroll
      for (int off = 1; off < 16; off <<= 1)
        sum += __shfl_xor(sum, off, 64);
      sum += __expf(sinkv - m);
      const float inv = 1.f / sum;
#pragma unroll
      for (int nf = 0; nf < 10; ++nf) {
        const int col = nf * 16 + cl;
        const int chunk = col >> 3;
        *reinterpret_cast<bf16*>(Ps + rowb * 384 + ((chunk ^ (rowb & 7)) << 4) + (cl & 7) * 2) =
            __float2bfloat16(pv[nf] * inv);
      }
    }

  // V staged (vmcnt) + P visible (lgkm); block-wide barrier before reading Vs
  asm volatile("s_waitcnt vmcnt(0) lgkmcnt(0)" ::: "memory");
  __builtin_amdgcn_sched_barrier(0);
  __syncthreads();

  // ---- PV: A = P (per-wave LDS), B = V (shared LDS) ----
  f32x4 oacc[2][4];
#pragma unroll
  for (int qf = 0; qf < 2; ++qf)
#pragma unroll
    for (int j = 0; j < 4; ++j) oacc[qf][j] = f32x4{0.f, 0.f, 0.f, 0.f};

#pragma unroll
  for (int ks = 0; ks < 5; ++ks) {
    bf16x8 pa[2];
#pragma unroll
    for (int qf = 0; qf < 2; ++qf) {
      const int row = qf * 16 + cl;
      const int chunk = ks * 4 + rg;
      pa[qf] = *reinterpret_cast<const bf16x8*>(
          Ps + row * 384 + ((chunk ^ (row & 7)) << 4));
    }
#pragma unroll
    for (int j = 0; j < 4; ++j) {
      const int d = j * 16 + cl;
      int slot = ks * 4 + rg + (d & 7);
      if (slot >= 20) slot -= 20;
      const bf16x8 bv = *reinterpret_cast<const bf16x8*>(Vs + d * 320 + slot * 16);
#pragma unroll
      for (int qf = 0; qf < 2; ++qf)
        oacc[qf][j] = __builtin_amdgcn_mfma_f32_16x16x32_bf16(pa[qf], bv, oacc[qf][j], 0, 0, 0);
    }
  }

  // ---- O -> per-wave P slab (dead), XOR-swizzled, then coalesced store ----
#pragma unroll
  for (int qf = 0; qf < 2; ++qf)
#pragma unroll
    for (int j = 0; j < 4; ++j)
#pragma unroll
      for (int r = 0; r < 4; ++r) {
        const int row = qf * 16 + rg * 4 + r;
        const int colb = (j * 16 + cl) * 2;   // byte in 128B row
        *reinterpret_cast<bf16*>(Ps + row * 384 + (colb ^ ((row & 7) << 4))) =
            __float2bfloat16(oacc[qf][j][r]);
      }
  __syncthreads();

  // block's out tile: [32 rows][256 cols] = rows of 512B, fully coalesced uint4 stores
#pragma unroll
  for (int p = 0; p < 4; ++p) {
    const int idx = p * 256 + t;
    const int row = idx >> 5;                 // 32 rows
    const int j16 = idx & 31;                 // 32 x 16B per row
    const int w2 = j16 >> 3, c8 = j16 & 7;
    const uint4 v = *reinterpret_cast<const uint4*>(
        smem + 20480 + w2 * 12288 + row * 384 + ((c8 * 16) ^ ((row & 7) << 4)));
    *reinterpret_cast<uint4*>(aout + (size_t)(q0 + row) * 2048 + hk * 256 + j16 * 8) = v;
  }
}

// ---------------- launch ----------------
extern "C" void kernel_launch(void* const* d_in, const int* in_sizes, int n_in,
                              void* d_out, int out_size, void* d_ws, size_t ws_size,
                              hipStream_t stream) {
  const float* x     = (const float*)d_in[0];
  const float* w1    = (const float*)d_in[1];
  const float* b1    = (const float*)d_in[2];
  const float* w2    = (const float*)d_in[3];
  const float* b2    = (const float*)d_in[4];
  const float* sinks = (const float*)d_in[5];
  const float* cosT  = (const float*)d_in[6];
  const float* sinT  = (const float*)d_in[7];
  float* out = (float*)d_out;

  char* ws = (char*)d_ws;
  bf16* xb   = (bf16*)(ws);                  // [2048][2048] 8 MB
  bf16* w1t  = (bf16*)(ws + 8388608);        // [3072][2048] 12 MB
  bf16* w2t  = (bf16*)(ws + 20971520);       // [2048][2048] 8 MB
  bf16* qbuf = (bf16*)(ws + 29360128);       // [2048][2048] 8 MB (raw Q; RoPE in attn)
  bf16* kbuf = (bf16*)(ws + 37748736);       // [2048][512]  2 MB (raw K; RoPE in attn)
  bf16* vt   = (bf16*)(ws + 39845888);       // [512][2048]  2 MB
  bf16* attn = (bf16*)(ws + 41943040);       // [2048][2048] 8 MB
  (void)in_sizes; (void)n_in; (void)out_size; (void)ws_size;

  prep_kernel<<<14336, 256, 0, stream>>>(x, w1, w2, xb, w1t, w2t);
  gemm1_kernel<<<256, 512, 122880, stream>>>(xb, w1t, b1, qbuf, kbuf, vt);
  attn_kernel<<<dim3(8, 64), 256, 69632, stream>>>(qbuf, kbuf, vt, sinks, cosT, sinT, attn);
  gemm2_kernel<<<256, 512, 98304, stream>>>(attn, w2t, b2, out);
}